// Round 2
// baseline (465.290 us; speedup 1.0000x reference)
//
#include <hip/hip_runtime.h>
#include <stdint.h>

// Problem constants
#define B 2048
#define S 201
#define HALF 100                 // S/2
#define D 128
#define BS (B * S)               // 411648
#define OFF_POS (BS * D)         // 52690944  : pos_enc starts here (floats)
#define OFF_VT  (2 * OFF_POS)    // 105381888 : visited_time (floats)
#define OFF_T2  (OFF_VT + BS)    // 105793536 : top2 (floats, 2 per bs)
#define EMB_F4  (BS * (D / 4))   // 13172736  : float4 elements per [B,S,D] tensor

#define NCH 32                   // chase blocks: 64 batches each => 2048 batches
#define NEMB 2016
#define NB1 (NCH + NEMB)
#define TPB 256

typedef float  vf4 __attribute__((ext_vector_type(4)));  // native vec for nontemporal
typedef float  vf2 __attribute__((ext_vector_type(2)));

// Kernel 1: blocks [0,NCH) run the per-batch pointer chase (one lane = one batch,
// wave 0 of the block; all 256 threads help stage/dump). Blocks [NCH,..) stream
// x_embedding = x @ W^T (write-BW bound) — independent of the chase, so the
// chase latency hides under the streaming writes.
__global__ __launch_bounds__(TPB) void k1(const float* __restrict__ x,
                                          const int* __restrict__ sol,
                                          const float* __restrict__ W,
                                          float* __restrict__ out,
                                          uint8_t* __restrict__ vt_ws) {
    if (blockIdx.x < NCH) {
        // per-lane private LDS state, 64 lanes per block
        __shared__ uint8_t  s_sol[64 * S];        // 12864 B
        __shared__ uint8_t  s_nx [64 * (HALF+1)]; //  6464 B
        __shared__ uint8_t  s_pv [64 * (HALF+1)]; //  6464 B
        __shared__ uint8_t  s_vis[64 * S];        // 12864 B
        __shared__ uint16_t s_t2 [64 * S];        // 25728 B  -> total 64384 B
        const int tid = threadIdx.x;
        const int b0  = blockIdx.x * 64;

        // stage sol (coalesced int32 loads -> u8 LDS) + zero-init vis/t2
        for (int idx = tid; idx < 64 * S; idx += TPB) {
            s_sol[idx] = (uint8_t)sol[b0 * S + idx];
            s_vis[idx] = 0;
            s_t2[idx]  = 0;
        }
        __syncthreads();

        if (tid < 64) {
            uint8_t*  sl  = s_sol + tid * S;
            uint8_t*  nx  = s_nx  + tid * (HALF + 1);
            uint8_t*  pv  = s_pv  + tid * (HALF + 1);
            uint8_t*  vis = s_vis + tid * S;
            uint16_t* t2  = s_t2  + tid * S;

            int pre = 0;
            int head = 0, second = 1;     // invariant: head==0 -> second==1; 1 open -> second==0
            unsigned long long m0 = 0, m1 = 0;  // in-list bitmask for pickups 1..100

            for (int i = 0; i < S; ++i) {
                int cur = sl[pre];
                vis[cur] = (uint8_t)(i + 1);
                if (cur != 0) {
                    if (cur <= HALF) {
                        // push: new element is the new maximum (time i+1)
                        nx[cur]  = (uint8_t)head;
                        pv[head] = (uint8_t)cur;   // pv[0] harmless
                        second = head;
                        head   = cur;
                        if (cur < 64) m0 |= 1ull << cur; else m1 |= 1ull << (cur - 64);
                    } else {
                        int q = cur - HALF;        // 1..100
                        bool in = (q < 64) ? ((m0 >> q) & 1ull) : ((m1 >> (q - 64)) & 1ull);
                        if (in) {
                            if (q < 64) m0 &= ~(1ull << q); else m1 &= ~(1ull << (q - 64));
                            if (q == head) {
                                head = second;
                                second = (head == 0) ? 1 : (int)nx[head];
                            } else if (q == second) {
                                int n2 = nx[q];
                                nx[head] = (uint8_t)n2;
                                pv[n2]   = (uint8_t)head;
                                second = n2;
                            } else {
                                int p = pv[q], n2 = nx[q];
                                nx[p]  = (uint8_t)n2;
                                pv[n2] = (uint8_t)p;
                            }
                        }
                    }
                }
                t2[cur] = (uint16_t)(head | (second << 8));
                pre = cur;
            }
        }
        __syncthreads();

        // dump: vt as float + u8(ws for k2), top2 as float2 — all coalesced
        for (int idx = tid; idx < 64 * S; idx += TPB) {
            int v = s_vis[idx];
            out[OFF_VT + b0 * S + idx] = (float)v;
            vt_ws[b0 * S + idx] = (uint8_t)v;
            int t = s_t2[idx];
            vf2 f2 = { (float)(t & 255), (float)(t >> 8) };
            __builtin_nontemporal_store(f2, ((vf2*)(out + OFF_T2)) + b0 * S + idx);
        }
    } else {
        // x_embedding: out[bs][d] = x[bs][0]*W[d][0] + x[bs][1]*W[d][1]
        const int d4 = (int)(threadIdx.x & 31);   // stride is a multiple of 32
        const float4* W4 = (const float4*)W;
        float4 w0 = W4[d4 * 2];      // {W[4d4][0],W[4d4][1],W[4d4+1][0],W[4d4+1][1]}
        float4 w1 = W4[d4 * 2 + 1];
        const float2* x2 = (const float2*)x;
        vf4* o4 = (vf4*)out;
        const int stride = NEMB * TPB;
        for (int idx4 = (int)(blockIdx.x - NCH) * TPB + (int)threadIdx.x;
             idx4 < EMB_F4; idx4 += stride) {
            float2 xv = x2[idx4 >> 5];
            vf4 o;
            o.x = xv.x * w0.x + xv.y * w0.y;
            o.y = xv.x * w0.z + xv.y * w0.w;
            o.z = xv.x * w1.x + xv.y * w1.y;
            o.w = xv.x * w1.z + xv.y * w1.w;
            __builtin_nontemporal_store(o, &o4[idx4]);
        }
    }
}

// Kernel 2: pos_enc[bs][:] = pattern[vt[bs] % S][:]  (pattern is 103 KB, L2-resident)
__global__ __launch_bounds__(TPB) void k2(const float* __restrict__ pattern,
                                          const uint8_t* __restrict__ vt_ws,
                                          float* __restrict__ out) {
    const vf4* p4 = (const vf4*)pattern;
    vf4* o4 = (vf4*)(out + OFF_POS);
    const int stride = (int)(gridDim.x * blockDim.x);
    for (int idx4 = (int)(blockIdx.x * blockDim.x + threadIdx.x);
         idx4 < EMB_F4; idx4 += stride) {
        int vt = vt_ws[idx4 >> 5];           // 1..201
        int row = (vt >= S) ? (vt - S) : vt; // vt % S
        vf4 v = p4[row * 32 + (idx4 & 31)];
        __builtin_nontemporal_store(v, &o4[idx4]);
    }
}

extern "C" void kernel_launch(void* const* d_in, const int* in_sizes, int n_in,
                              void* d_out, int out_size, void* d_ws, size_t ws_size,
                              hipStream_t stream) {
    const float* x       = (const float*)d_in[0];   // [2048,201,2] f32
    const int*   sol     = (const int*)d_in[1];     // [2048,201] int
    const float* W       = (const float*)d_in[2];   // [128,2] f32
    const float* pattern = (const float*)d_in[3];   // [201,128] f32
    float* out = (float*)d_out;
    uint8_t* vt_ws = (uint8_t*)d_ws;                // 411648 bytes staging

    hipLaunchKernelGGL(k1, dim3(NB1), dim3(TPB), 0, stream, x, sol, W, out, vt_ws);
    hipLaunchKernelGGL(k2, dim3(2048), dim3(TPB), 0, stream, pattern, vt_ws, out);
}